// Round 6
// baseline (565.411 us; speedup 1.0000x reference)
//
#include <hip/hip_runtime.h>
#include <hip/hip_bf16.h>

#define T_SEQ   512
#define H_DIM   128
#define N3H     384
#define HS      136   // h row stride (ushort): 272B; A-frag b128 reads conflict-free
#define XS      72    // x row stride (ushort), fallback kernel only

typedef float f32x4 __attribute__((ext_vector_type(4)));
typedef float f32x2 __attribute__((ext_vector_type(2)));
typedef float f32x4u __attribute__((ext_vector_type(4), aligned(4)));
typedef __bf16 bf16x8 __attribute__((ext_vector_type(8)));
typedef unsigned short us8 __attribute__((ext_vector_type(8)));
typedef unsigned short us4 __attribute__((ext_vector_type(4)));

static __device__ __forceinline__ unsigned short f2bf(float f) {
    unsigned int u = __builtin_bit_cast(unsigned int, f);
    u += 0x7FFFu + ((u >> 16) & 1u);
    return (unsigned short)(u >> 16);
}
static __device__ __forceinline__ float bf2f(unsigned short u) {
    return __builtin_bit_cast(float, ((unsigned int)u) << 16);
}

// LDS-only barrier: lgkmcnt(0) but vmcnt untouched -> global prefetch loads
// stay in flight across the barrier.
static __device__ __forceinline__ void lds_barrier() {
    asm volatile("" ::: "memory");
    __builtin_amdgcn_s_waitcnt(0xC07F);   // lgkmcnt(0), vmcnt/expcnt max
    __builtin_amdgcn_s_barrier();
    asm volatile("" ::: "memory");
}

static __device__ __forceinline__ bf16x8 ld8(const unsigned short* p) {
    return __builtin_bit_cast(bf16x8, *(const us8*)p);
}

// ---------------------------------------------------------------------------
// Pre-pass: xw[t][btile][tile 0..23][lane][4] = (x @ Wx + b_in) C-fragments,
// bf16.  Grid 1024 = 32 btiles x 32 t-chunks(16).  8 waves; wave w does
// tiles {w, 8+w, 16+w} for all 16 t.
// ---------------------------------------------------------------------------
__global__ __launch_bounds__(512, 1) void xw_prepass(
    const float* __restrict__ inputs, const float* __restrict__ Wx,
    const float* __restrict__ bias, unsigned short* __restrict__ xwbuf)
{
    const int tid  = threadIdx.x;
    const int w    = tid >> 6;
    const int lane = tid & 63;
    const int m    = lane & 15;
    const int q    = lane >> 4;
    const int bt   = blockIdx.x & 31;
    const int tc   = blockIdx.x >> 5;
    const int b0   = bt * 16;

    bf16x8 wxB[3][2];
    float bin[3];
#pragma unroll
    for (int g = 0; g < 3; ++g) {
        const int col = (8 * g + w) * 16 + m;
#pragma unroll
        for (int k = 0; k < 2; ++k) {
            us8 tmp;
#pragma unroll
            for (int j = 0; j < 8; ++j) tmp[j] = f2bf(Wx[(32 * k + 8 * q + j) * N3H + col]);
            wxB[g][k] = __builtin_bit_cast(bf16x8, tmp);
        }
        bin[g] = bias[col];
    }

    const float* xr = inputs + ((size_t)(b0 + m) * T_SEQ + (size_t)tc * 16) * 65;

    for (int tt = 0; tt < 16; ++tt) {
        const int t = tc * 16 + tt;
        bf16x8 xa[2];
#pragma unroll
        for (int k = 0; k < 2; ++k) {
            f32x4u lo = *(const f32x4u*)(xr + (size_t)tt * 65 + 32 * k + 8 * q);
            f32x4u hi = *(const f32x4u*)(xr + (size_t)tt * 65 + 32 * k + 8 * q + 4);
            us8 tmp;
#pragma unroll
            for (int j = 0; j < 4; ++j) { tmp[j] = f2bf(lo[j]); tmp[4 + j] = f2bf(hi[j]); }
            xa[k] = __builtin_bit_cast(bf16x8, tmp);
        }
#pragma unroll
        for (int g = 0; g < 3; ++g) {
            f32x4 acc = { bin[g], bin[g], bin[g], bin[g] };
            acc = __builtin_amdgcn_mfma_f32_16x16x32_bf16(xa[0], wxB[g][0], acc, 0, 0, 0);
            acc = __builtin_amdgcn_mfma_f32_16x16x32_bf16(xa[1], wxB[g][1], acc, 0, 0, 0);
            us4 o; o[0] = f2bf(acc[0]); o[1] = f2bf(acc[1]); o[2] = f2bf(acc[2]); o[3] = f2bf(acc[3]);
            *(us4*)(xwbuf + (((size_t)t * 32 + bt) * 24 + (8 * g + w)) * 256 + lane * 4) = o;
        }
    }
}

// ---------------------------------------------------------------------------
// GRU serial loop, xw from global (pre-pass).  32 blocks x 512 threads.
// ---------------------------------------------------------------------------
__global__ __launch_bounds__(512, 1) void gru_fused_pre(
    const float* __restrict__ inputs, const float* __restrict__ Wh,
    const float* __restrict__ bias, const unsigned short* __restrict__ xwbuf,
    const float* __restrict__ W_state, const float* __restrict__ w1,
    const float* __restrict__ b1, const float* __restrict__ gamma,
    const float* __restrict__ beta, const float* __restrict__ mean,
    const float* __restrict__ var, const float* __restrict__ w2,
    const float* __restrict__ b2, float* __restrict__ out)
{
    __shared__ __attribute__((aligned(16))) unsigned short hb[2][16 * HS];
    __shared__ float hf[16][H_DIM + 1];

    const int tid  = threadIdx.x;
    const int w    = tid >> 6;
    const int lane = tid & 63;
    const int m    = lane & 15;
    const int q    = lane >> 4;
    const int b0   = blockIdx.x * 16;

    bf16x8 whB[3][4];
    float brec[3];
#pragma unroll
    for (int g = 0; g < 3; ++g) {
        const int col = (8 * g + w) * 16 + m;
#pragma unroll
        for (int k = 0; k < 4; ++k) {
            us8 tmp;
#pragma unroll
            for (int j = 0; j < 8; ++j) tmp[j] = f2bf(Wh[(32 * k + 8 * q + j) * N3H + col]);
            whB[g][k] = __builtin_bit_cast(bf16x8, tmp);
        }
        brec[g] = bias[N3H + col];
    }

    int hro[4];
#pragma unroll
    for (int k = 0; k < 4; ++k) hro[k] = m * HS + 32 * k + 8 * q;
    const int hw_base = (4 * q) * HS + 16 * w + m;

    // xw fragment pointers (us4 units; one us4 = this lane's 4-elem frag)
    const us4* xwb[3];
#pragma unroll
    for (int g = 0; g < 3; ++g)
        xwb[g] = (const us4*)xwbuf + ((size_t)blockIdx.x * 24 + (8 * g + w)) * 64 + lane;
    const size_t TSTRIDE = (size_t)32 * 24 * 64;   // us4 per t

    // zero h(0)
    {
        unsigned int* p = (unsigned int*)hb[0];
        for (int i = tid; i < 16 * HS / 2; i += 512) p[i] = 0;
    }

    // preload xw(0), xw(1)
    us4 slot[2][3];
#pragma unroll
    for (int g = 0; g < 3; ++g) {
        slot[0][g] = xwb[g][0];
        slot[1][g] = xwb[g][TSTRIDE];
    }

    f32x4 hreg = { 0.f, 0.f, 0.f, 0.f };
    const float K1 = -1.4426950408889634f;
    const float K2 = -2.8853900817779268f;

    auto step = [&](int t, int p, const unsigned short* hcur, unsigned short* hnxt) {
        // unpack xw(t) (loads issued 2 steps ago; vmcnt wait is free)
        f32x4 xwf[3];
#pragma unroll
        for (int g = 0; g < 3; ++g)
#pragma unroll
            for (int i = 0; i < 4; ++i) xwf[g][i] = bf2f(slot[p][g][i]);
        // refill slot with xw(t+2) — stays in flight across barrier (vmcnt only)
        if (t + 2 < T_SEQ) {
#pragma unroll
            for (int g = 0; g < 3; ++g) slot[p][g] = xwb[g][(size_t)(t + 2) * TSTRIDE];
        }

        lds_barrier();

        bf16x8 ha[4];
#pragma unroll
        for (int k = 0; k < 4; ++k) ha[k] = ld8(&hcur[hro[k]]);
        f32x4 racc[3];
#pragma unroll
        for (int g = 0; g < 3; ++g) {
            f32x4 a1 = { brec[g], brec[g], brec[g], brec[g] };
            a1 = __builtin_amdgcn_mfma_f32_16x16x32_bf16(ha[0], whB[g][0], a1, 0, 0, 0);
            a1 = __builtin_amdgcn_mfma_f32_16x16x32_bf16(ha[1], whB[g][1], a1, 0, 0, 0);
            f32x4 a2 = { 0.f, 0.f, 0.f, 0.f };
            a2 = __builtin_amdgcn_mfma_f32_16x16x32_bf16(ha[2], whB[g][2], a2, 0, 0, 0);
            a2 = __builtin_amdgcn_mfma_f32_16x16x32_bf16(ha[3], whB[g][3], a2, 0, 0, 0);
            racc[g] = a1 + a2;
        }

        f32x4 hnew;
#pragma unroll
        for (int i = 0; i < 4; ++i) {
            const float ea = __builtin_amdgcn_exp2f(K1 * (xwf[0][i] + racc[0][i]));
            const float eb = __builtin_amdgcn_exp2f(K1 * (xwf[1][i] + racc[1][i]));
            const float Pa = 1.0f + ea, Pb = 1.0f + eb;
            const float D  = __builtin_amdgcn_rcpf(Pa * Pb);
            const float z  = Pb * D;
            const float r  = Pa * D;
            float u = __builtin_amdgcn_fmed3f(xwf[2][i] + r * racc[2][i], -15.0f, 15.0f);
            const float ec = __builtin_amdgcn_exp2f(K2 * u);
            const float T  = (1.0f - ec) * __builtin_amdgcn_rcpf(1.0f + ec);
            hnew[i] = T + z * (hreg[i] - T);
        }
        hreg = hnew;
#pragma unroll
        for (int i = 0; i < 4; ++i) hnxt[hw_base + i * HS] = f2bf(hnew[i]);
    };

    for (int t = 0; t < T_SEQ; t += 2) {
        step(t,     0, hb[0], hb[1]);
        step(t + 1, 1, hb[1], hb[0]);
    }

    // ---- fused tail ----
#pragma unroll
    for (int i = 0; i < 4; ++i) hf[4 * q + i][16 * w + m] = hreg[i];
    __syncthreads();
    {
        const int row = tid >> 5;
        const int c0  = (tid & 31) * 4;
        const float sf = inputs[((size_t)(b0 + row) * T_SEQ + (T_SEQ - 1)) * 65 + 64];
        int si = (int)sf;
        si = si < 0 ? 0 : (si > 2 ? 2 : si);
#pragma unroll
        for (int c = 0; c < 4; ++c) hf[row][c0 + c] += W_state[si * H_DIM + c0 + c];
    }
    __syncthreads();
    {
        const int row = tid >> 5;
        const int jj  = (tid & 31) * 2;
        f32x2 acc = { b1[jj], b1[jj + 1] };
        for (int k = 0; k < H_DIM; ++k) {
            const float hv = hf[row][k];
            const f32x2 wv = *(const f32x2*)(w1 + k * 64 + jj);
            acc[0] = fmaf(hv, wv[0], acc[0]);
            acc[1] = fmaf(hv, wv[1], acc[1]);
        }
        float v = 0.0f;
#pragma unroll
        for (int ii = 0; ii < 2; ++ii) {
            const int j = jj + ii;
            float a = fmaxf(acc[ii], 0.0f);
            a = (a - mean[j]) * rsqrtf(var[j] + 1e-3f) * gamma[j] + beta[j];
            v = fmaf(a, w2[j], v);
        }
        v += __shfl_down(v, 16);
        v += __shfl_down(v, 8);
        v += __shfl_down(v, 4);
        v += __shfl_down(v, 2);
        v += __shfl_down(v, 1);
        if ((tid & 31) == 0) out[b0 + row] = v + b2[0];
    }
}

// ---------------------------------------------------------------------------
// Fallback (R5 kernel, proven): used only if ws_size can't hold the xw buffer.
// ---------------------------------------------------------------------------
__global__ __launch_bounds__(512, 1) void gru_fused_fb(
    const float* __restrict__ inputs, const float* __restrict__ Wx,
    const float* __restrict__ Wh, const float* __restrict__ bias,
    const float* __restrict__ W_state, const float* __restrict__ w1,
    const float* __restrict__ b1, const float* __restrict__ gamma,
    const float* __restrict__ beta, const float* __restrict__ mean,
    const float* __restrict__ var, const float* __restrict__ w2,
    const float* __restrict__ b2, float* __restrict__ out)
{
    __shared__ __attribute__((aligned(16))) unsigned short hb[2][16 * HS];
    __shared__ __attribute__((aligned(16))) unsigned short xb[2][16 * XS];
    __shared__ float hf[16][H_DIM + 1];

    const int tid  = threadIdx.x;
    const int w    = tid >> 6;
    const int lane = tid & 63;
    const int m    = lane & 15;
    const int q    = lane >> 4;
    const int b0   = blockIdx.x * 16;

    bf16x8 whB[3][4];
    bf16x8 wxB[3][2];
    float brec[3], bin[3];
#pragma unroll
    for (int g = 0; g < 3; ++g) {
        const int col = (8 * g + w) * 16 + m;
#pragma unroll
        for (int k = 0; k < 4; ++k) {
            us8 tmp;
#pragma unroll
            for (int j = 0; j < 8; ++j) tmp[j] = f2bf(Wh[(32 * k + 8 * q + j) * N3H + col]);
            whB[g][k] = __builtin_bit_cast(bf16x8, tmp);
        }
#pragma unroll
        for (int k = 0; k < 2; ++k) {
            us8 tmp;
#pragma unroll
            for (int j = 0; j < 8; ++j) tmp[j] = f2bf(Wx[(32 * k + 8 * q + j) * N3H + col]);
            wxB[g][k] = __builtin_bit_cast(bf16x8, tmp);
        }
        bin[g]  = bias[col];
        brec[g] = bias[N3H + col];
    }

    int hro[4], xro[2];
#pragma unroll
    for (int k = 0; k < 4; ++k) hro[k] = m * HS + 32 * k + 8 * q;
#pragma unroll
    for (int k = 0; k < 2; ++k) xro[k] = m * XS + 32 * k + 8 * q;
    const int hw_base = (4 * q) * HS + 16 * w + m;

    const int sr = tid >> 4, sc = tid & 15;
    const int xwoff = sr * XS + sc * 4;
    const float* xsrc = inputs + ((size_t)(b0 + sr) * T_SEQ) * 65 + sc * 4;

    auto xpack = [&](f32x4u v) -> us4 {
        us4 r; r[0] = f2bf(v[0]); r[1] = f2bf(v[1]); r[2] = f2bf(v[2]); r[3] = f2bf(v[3]);
        return r;
    };

    {
        unsigned int* p = (unsigned int*)hb[0];
        for (int i = tid; i < 16 * HS / 2; i += 512) p[i] = 0;
    }
    if (tid < 256) {
        f32x4u v0 = *(const f32x4u*)(xsrc + 0 * 65);
        f32x4u v1 = *(const f32x4u*)(xsrc + 1 * 65);
        *(us4*)&xb[0][xwoff] = xpack(v0);
        *(us4*)&xb[1][xwoff] = xpack(v1);
    }
    lds_barrier();

    f32x4 xwA[3], xwB[3];
    {
        bf16x8 xa[2];
#pragma unroll
        for (int k = 0; k < 2; ++k) xa[k] = ld8(&xb[0][xro[k]]);
#pragma unroll
        for (int g = 0; g < 3; ++g) {
            f32x4 acc = { bin[g], bin[g], bin[g], bin[g] };
            acc = __builtin_amdgcn_mfma_f32_16x16x32_bf16(xa[0], wxB[g][0], acc, 0, 0, 0);
            acc = __builtin_amdgcn_mfma_f32_16x16x32_bf16(xa[1], wxB[g][1], acc, 0, 0, 0);
            xwA[g] = acc;
        }
    }

    f32x4u pf0 = {}, pf1 = {};
    if (tid < 256) pf0 = *(const f32x4u*)(xsrc + 2 * 65);

    f32x4 hreg = { 0.f, 0.f, 0.f, 0.f };
    const float K1 = -1.4426950408889634f;
    const float K2 = -2.8853900817779268f;

    auto step = [&](int t, f32x4* xw_cur, f32x4* xw_next,
                    f32x4u& pfLoad, f32x4u& pfUse,
                    const unsigned short* hcur, unsigned short* hnxt,
                    const unsigned short* xnxt, unsigned short* xwr) {
        if (tid < 256 && t <= T_SEQ - 4) pfLoad = *(const f32x4u*)(xsrc + (t + 3) * 65);
        lds_barrier();
        bf16x8 ha[4];
#pragma unroll
        for (int k = 0; k < 4; ++k) ha[k] = ld8(&hcur[hro[k]]);
        f32x4 racc[3];
#pragma unroll
        for (int g = 0; g < 3; ++g) {
            f32x4 a1 = { brec[g], brec[g], brec[g], brec[g] };
            a1 = __builtin_amdgcn_mfma_f32_16x16x32_bf16(ha[0], whB[g][0], a1, 0, 0, 0);
            a1 = __builtin_amdgcn_mfma_f32_16x16x32_bf16(ha[1], whB[g][1], a1, 0, 0, 0);
            f32x4 a2 = { 0.f, 0.f, 0.f, 0.f };
            a2 = __builtin_amdgcn_mfma_f32_16x16x32_bf16(ha[2], whB[g][2], a2, 0, 0, 0);
            a2 = __builtin_amdgcn_mfma_f32_16x16x32_bf16(ha[3], whB[g][3], a2, 0, 0, 0);
            racc[g] = a1 + a2;
        }
        if (t < T_SEQ - 1) {
            bf16x8 xa[2];
#pragma unroll
            for (int k = 0; k < 2; ++k) xa[k] = ld8(&xnxt[xro[k]]);
#pragma unroll
            for (int g = 0; g < 3; ++g) {
                f32x4 acc = { bin[g], bin[g], bin[g], bin[g] };
                acc = __builtin_amdgcn_mfma_f32_16x16x32_bf16(xa[0], wxB[g][0], acc, 0, 0, 0);
                acc = __builtin_amdgcn_mfma_f32_16x16x32_bf16(xa[1], wxB[g][1], acc, 0, 0, 0);
                xw_next[g] = acc;
            }
        }
        f32x4 hnew;
#pragma unroll
        for (int i = 0; i < 4; ++i) {
            const float ea = __builtin_amdgcn_exp2f(K1 * (xw_cur[0][i] + racc[0][i]));
            const float eb = __builtin_amdgcn_exp2f(K1 * (xw_cur[1][i] + racc[1][i]));
            const float Pa = 1.0f + ea, Pb = 1.0f + eb;
            const float D  = __builtin_amdgcn_rcpf(Pa * Pb);
            const float z  = Pb * D;
            const float r  = Pa * D;
            float u = __builtin_amdgcn_fmed3f(xw_cur[2][i] + r * racc[2][i], -15.0f, 15.0f);
            const float ec = __builtin_amdgcn_exp2f(K2 * u);
            const float T  = (1.0f - ec) * __builtin_amdgcn_rcpf(1.0f + ec);
            hnew[i] = T + z * (hreg[i] - T);
        }
        hreg = hnew;
#pragma unroll
        for (int i = 0; i < 4; ++i) hnxt[hw_base + i * HS] = f2bf(hnew[i]);
        if (tid < 256 && t <= T_SEQ - 3) *(us4*)&xwr[xwoff] = xpack(pfUse);
    };

    for (int t = 0; t < T_SEQ; t += 2) {
        step(t,     xwA, xwB, pf1, pf0, hb[0], hb[1], xb[1], xb[0]);
        step(t + 1, xwB, xwA, pf0, pf1, hb[1], hb[0], xb[0], xb[1]);
    }

#pragma unroll
    for (int i = 0; i < 4; ++i) hf[4 * q + i][16 * w + m] = hreg[i];
    __syncthreads();
    {
        const int row = tid >> 5;
        const int c0  = (tid & 31) * 4;
        const float sf = inputs[((size_t)(b0 + row) * T_SEQ + (T_SEQ - 1)) * 65 + 64];
        int si = (int)sf;
        si = si < 0 ? 0 : (si > 2 ? 2 : si);
#pragma unroll
        for (int c = 0; c < 4; ++c) hf[row][c0 + c] += W_state[si * H_DIM + c0 + c];
    }
    __syncthreads();
    {
        const int row = tid >> 5;
        const int jj  = (tid & 31) * 2;
        f32x2 acc = { b1[jj], b1[jj + 1] };
        for (int k = 0; k < H_DIM; ++k) {
            const float hv = hf[row][k];
            const f32x2 wv = *(const f32x2*)(w1 + k * 64 + jj);
            acc[0] = fmaf(hv, wv[0], acc[0]);
            acc[1] = fmaf(hv, wv[1], acc[1]);
        }
        float v = 0.0f;
#pragma unroll
        for (int ii = 0; ii < 2; ++ii) {
            const int j = jj + ii;
            float a = fmaxf(acc[ii], 0.0f);
            a = (a - mean[j]) * rsqrtf(var[j] + 1e-3f) * gamma[j] + beta[j];
            v = fmaf(a, w2[j], v);
        }
        v += __shfl_down(v, 16);
        v += __shfl_down(v, 8);
        v += __shfl_down(v, 4);
        v += __shfl_down(v, 2);
        v += __shfl_down(v, 1);
        if ((tid & 31) == 0) out[b0 + row] = v + b2[0];
    }
}

extern "C" void kernel_launch(void* const* d_in, const int* in_sizes, int n_in,
                              void* d_out, int out_size, void* d_ws, size_t ws_size,
                              hipStream_t stream) {
    (void)in_sizes; (void)n_in; (void)out_size;
    const float* inputs  = (const float*)d_in[0];
    const float* Wx      = (const float*)d_in[1];
    const float* Wh      = (const float*)d_in[2];
    const float* bias    = (const float*)d_in[3];
    const float* W_state = (const float*)d_in[4];
    const float* w1      = (const float*)d_in[5];
    const float* b1      = (const float*)d_in[6];
    const float* gamma   = (const float*)d_in[7];
    const float* beta    = (const float*)d_in[8];
    const float* mean    = (const float*)d_in[9];
    const float* var     = (const float*)d_in[10];
    const float* w2      = (const float*)d_in[11];
    const float* b2      = (const float*)d_in[12];
    float* out = (float*)d_out;

    const size_t xw_bytes = (size_t)T_SEQ * 32 * 24 * 256 * sizeof(unsigned short); // 192 MiB
    if (ws_size >= xw_bytes) {
        unsigned short* xwbuf = (unsigned short*)d_ws;
        xw_prepass<<<1024, 512, 0, stream>>>(inputs, Wx, bias, xwbuf);
        gru_fused_pre<<<32, 512, 0, stream>>>(inputs, Wh, bias, xwbuf, W_state,
                                              w1, b1, gamma, beta, mean, var,
                                              w2, b2, out);
    } else {
        gru_fused_fb<<<32, 512, 0, stream>>>(inputs, Wx, Wh, bias, W_state, w1,
                                             b1, gamma, beta, mean, var, w2, b2,
                                             out);
    }
}

// Round 7
// 475.950 us; speedup vs baseline: 1.1880x; 1.1880x over previous
//
#include <hip/hip_runtime.h>
#include <hip/hip_bf16.h>

#define T_SEQ   512
#define H_DIM   128
#define N3H     384
#define HSW     128   // h row stride (ushort): 256B rows + 16B-chunk XOR swizzle
#define XS      72    // x row stride (ushort): 144B -> rotation, conflict-free

typedef float f32x4 __attribute__((ext_vector_type(4)));
typedef float f32x2 __attribute__((ext_vector_type(2)));
typedef float f32x4u __attribute__((ext_vector_type(4), aligned(4)));
typedef __bf16 bf16x8 __attribute__((ext_vector_type(8)));
typedef unsigned short us8 __attribute__((ext_vector_type(8)));
typedef unsigned short us4 __attribute__((ext_vector_type(4)));

static __device__ __forceinline__ unsigned short f2bf(float f) {
    unsigned int u = __builtin_bit_cast(unsigned int, f);
    u += 0x7FFFu + ((u >> 16) & 1u);
    return (unsigned short)(u >> 16);
}

// LDS-only barrier: lgkmcnt(0), vmcnt untouched -> global prefetch loads
// stay in flight across it.
static __device__ __forceinline__ void lds_barrier() {
    asm volatile("" ::: "memory");
    __builtin_amdgcn_s_waitcnt(0xC07F);
    __builtin_amdgcn_s_barrier();
    asm volatile("" ::: "memory");
}

static __device__ __forceinline__ bf16x8 ld8(const unsigned short* p) {
    return __builtin_bit_cast(bf16x8, *(const us8*)p);
}

// 32 blocks x 16 batch rows x 512 threads (8 waves, 2/SIMD).
// Wave w owns N-tiles {w, 8+w, 16+w}: z/r/hh for cols [16w,16w+16) wave-local.
// Gate pre-activations are computed PRE-SCALED: z,r rows of Wx/Wh/b scaled by
// -1/ln2 (so sigmoid = 1/(1+exp2(a))), hh rows scaled by +2/ln2 (so
// tanh(u) = 1 - 2/(1+exp2(u'))), removing all multiplies before exp2.
__global__ __launch_bounds__(512, 1) void gru_fused(
    const float* __restrict__ inputs, const float* __restrict__ Wx,
    const float* __restrict__ Wh, const float* __restrict__ bias,
    const float* __restrict__ W_state, const float* __restrict__ w1,
    const float* __restrict__ b1, const float* __restrict__ gamma,
    const float* __restrict__ beta, const float* __restrict__ mean,
    const float* __restrict__ var, const float* __restrict__ w2,
    const float* __restrict__ b2, float* __restrict__ out)
{
    __shared__ __attribute__((aligned(16))) unsigned short hb[2][16 * HSW];
    __shared__ __attribute__((aligned(16))) unsigned short xb[2][16 * XS];
    __shared__ float hf[16][H_DIM + 1];

    const int tid  = threadIdx.x;
    const int w    = tid >> 6;      // wave 0..7
    const int lane = tid & 63;
    const int m    = lane & 15;
    const int q    = lane >> 4;
    const int b0   = blockIdx.x * 16;

    const float SCL0 = -1.4426950408889634f;  // -1/ln2  (z)
    const float SCL2 =  2.8853900817779268f;  // +2/ln2  (hh)

    // ---- prescaled weight B-fragments in registers for all 512 steps ----
    bf16x8 whB[3][4];
    bf16x8 wxB[3][2];
    float brec[3], bin[3];
#pragma unroll
    for (int g = 0; g < 3; ++g) {
        const float s = (g < 2) ? SCL0 : SCL2;
        const int col = (8 * g + w) * 16 + m;   // tile w / 8+w / 16+w
#pragma unroll
        for (int k = 0; k < 4; ++k) {
            us8 tmp;
#pragma unroll
            for (int j = 0; j < 8; ++j) tmp[j] = f2bf(s * Wh[(32 * k + 8 * q + j) * N3H + col]);
            whB[g][k] = __builtin_bit_cast(bf16x8, tmp);
        }
#pragma unroll
        for (int k = 0; k < 2; ++k) {
            us8 tmp;
#pragma unroll
            for (int j = 0; j < 8; ++j) tmp[j] = f2bf(s * Wx[(32 * k + 8 * q + j) * N3H + col]);
            wxB[g][k] = __builtin_bit_cast(bf16x8, tmp);
        }
        bin[g]  = s * bias[col];
        brec[g] = s * bias[N3H + col];
    }

    // loop-invariant LDS offsets (ushort units), XOR-swizzled h layout:
    // logical 16B-chunk c of row r lives at physical chunk c^(r&7).
    int hro[4], hwo[4], xro[2];
#pragma unroll
    for (int k = 0; k < 4; ++k) hro[k] = m * HSW + (((4 * k + q) ^ (m & 7)) * 8);
#pragma unroll
    for (int i = 0; i < 4; ++i) {
        const int row = 4 * q + i;
        hwo[i] = row * HSW + (((2 * w + (m >> 3)) ^ (row & 7)) * 8) + (m & 7);
    }
#pragma unroll
    for (int k = 0; k < 2; ++k) xro[k] = m * XS + 32 * k + 8 * q;

    // staging: threads 0..255 load one float4 (row sr, cols 4sc..4sc+3)
    const int sr = tid >> 4, sc = tid & 15;
    const int xwoff = sr * XS + sc * 4;
    const float* xsrc = inputs + ((size_t)(b0 + sr) * T_SEQ) * 65 + sc * 4;

    auto xpack = [&](f32x4u v) -> us4 {
        us4 r; r[0] = f2bf(v[0]); r[1] = f2bf(v[1]); r[2] = f2bf(v[2]); r[3] = f2bf(v[3]);
        return r;
    };

    // zero h(0)
    {
        unsigned int* p = (unsigned int*)hb[0];
        for (int i = tid; i < 16 * HSW / 2; i += 512) p[i] = 0;
    }
    // stage x(0), x(1)
    if (tid < 256) {
        f32x4u v0 = *(const f32x4u*)(xsrc + 0 * 65);
        f32x4u v1 = *(const f32x4u*)(xsrc + 1 * 65);
        *(us4*)&xb[0][xwoff] = xpack(v0);
        *(us4*)&xb[1][xwoff] = xpack(v1);
    }
    lds_barrier();

    // xw(0)
    f32x4 xwA[3], xwB[3];
    {
        bf16x8 xa[2];
#pragma unroll
        for (int k = 0; k < 2; ++k) xa[k] = ld8(&xb[0][xro[k]]);
#pragma unroll
        for (int g = 0; g < 3; ++g) {
            f32x4 acc = { bin[g], bin[g], bin[g], bin[g] };
            acc = __builtin_amdgcn_mfma_f32_16x16x32_bf16(xa[0], wxB[g][0], acc, 0, 0, 0);
            acc = __builtin_amdgcn_mfma_f32_16x16x32_bf16(xa[1], wxB[g][1], acc, 0, 0, 0);
            xwA[g] = acc;
        }
    }

    f32x4u pf0 = {}, pf1 = {};
    if (tid < 256) pf0 = *(const f32x4u*)(xsrc + 2 * 65);   // x(2)

    f32x4 hreg = { 0.f, 0.f, 0.f, 0.f };

    auto step = [&](int t, f32x4* xw_cur, f32x4* xw_next,
                    f32x4u& pfLoad, f32x4u& pfUse,
                    const unsigned short* hcur, unsigned short* hnxt,
                    const unsigned short* xnxt, unsigned short* xwr) {
        // global prefetch x(t+3) — spans the barrier (vmcnt not drained)
        if (tid < 256 && t <= T_SEQ - 4) pfLoad = *(const f32x4u*)(xsrc + (t + 3) * 65);

        lds_barrier();

        // issue all LDS reads up front (h fragments + next-step x fragments)
        bf16x8 ha[4];
#pragma unroll
        for (int k = 0; k < 4; ++k) ha[k] = ld8(&hcur[hro[k]]);
        bf16x8 xa[2];
        if (t < T_SEQ - 1) {
#pragma unroll
            for (int k = 0; k < 2; ++k) xa[k] = ld8(&xnxt[xro[k]]);
        }

        // rec(t) = h(t) @ Wh' (prescaled)  — two 2-deep chains per gate
        f32x4 racc[3];
#pragma unroll
        for (int g = 0; g < 3; ++g) {
            f32x4 a1 = { brec[g], brec[g], brec[g], brec[g] };
            a1 = __builtin_amdgcn_mfma_f32_16x16x32_bf16(ha[0], whB[g][0], a1, 0, 0, 0);
            a1 = __builtin_amdgcn_mfma_f32_16x16x32_bf16(ha[1], whB[g][1], a1, 0, 0, 0);
            f32x4 a2 = { 0.f, 0.f, 0.f, 0.f };
            a2 = __builtin_amdgcn_mfma_f32_16x16x32_bf16(ha[2], whB[g][2], a2, 0, 0, 0);
            a2 = __builtin_amdgcn_mfma_f32_16x16x32_bf16(ha[3], whB[g][3], a2, 0, 0, 0);
            racc[g] = a1 + a2;
        }

        // gates: a' already scaled.  z = 1/(1+exp2(az')), tanh = 1-2/(1+exp2(u'))
        f32x4 hnew;
#pragma unroll
        for (int i = 0; i < 4; ++i) {
            const float ea = __builtin_amdgcn_exp2f(xw_cur[0][i] + racc[0][i]);
            const float eb = __builtin_amdgcn_exp2f(xw_cur[1][i] + racc[1][i]);
            const float Pa = 1.0f + ea, Pb = 1.0f + eb;
            const float D  = __builtin_amdgcn_rcpf(Pa * Pb);
            const float z  = Pb * D;
            const float r  = Pa * D;
            const float u  = fmaf(r, racc[2][i], xw_cur[2][i]);
            const float ec = __builtin_amdgcn_exp2f(u);
            const float hh = fmaf(-2.0f, __builtin_amdgcn_rcpf(1.0f + ec), 1.0f);
            hnew[i] = fmaf(z, hreg[i] - hh, hh);
        }
        hreg = hnew;

        // xw(t+1) — independent; overlaps the gate VALU phase on the MFMA pipe
        if (t < T_SEQ - 1) {
#pragma unroll
            for (int g = 0; g < 3; ++g) {
                f32x4 acc = { bin[g], bin[g], bin[g], bin[g] };
                acc = __builtin_amdgcn_mfma_f32_16x16x32_bf16(xa[0], wxB[g][0], acc, 0, 0, 0);
                acc = __builtin_amdgcn_mfma_f32_16x16x32_bf16(xa[1], wxB[g][1], acc, 0, 0, 0);
                xw_next[g] = acc;
            }
        }

        // write h(t+1) (swizzled scatter)
#pragma unroll
        for (int i = 0; i < 4; ++i) hnxt[hwo[i]] = f2bf(hnew[i]);

        // stage x(t+2) into LDS at end of step (off the h critical path)
        if (tid < 256 && t <= T_SEQ - 3) *(us4*)&xwr[xwoff] = xpack(pfUse);
    };

    for (int t = 0; t < T_SEQ; t += 2) {
        step(t,     xwA, xwB, pf1, pf0, hb[0], hb[1], xb[1], xb[0]);
        step(t + 1, xwB, xwA, pf0, pf1, hb[1], hb[0], xb[0], xb[1]);
    }

    // ---- fused tail: +W_state, w1/ReLU/BN, w2 ----
#pragma unroll
    for (int i = 0; i < 4; ++i)
        hf[4 * q + i][16 * w + m] = hreg[i];
    __syncthreads();

    {
        const int row = tid >> 5;
        const int c0  = (tid & 31) * 4;
        const float sf = inputs[((size_t)(b0 + row) * T_SEQ + (T_SEQ - 1)) * 65 + 64];
        int si = (int)sf;
        si = si < 0 ? 0 : (si > 2 ? 2 : si);
#pragma unroll
        for (int c = 0; c < 4; ++c)
            hf[row][c0 + c] += W_state[si * H_DIM + c0 + c];
    }
    __syncthreads();

    {
        const int row = tid >> 5;
        const int jj  = (tid & 31) * 2;
        f32x2 acc = { b1[jj], b1[jj + 1] };
        for (int k = 0; k < H_DIM; ++k) {
            const float hv = hf[row][k];
            const f32x2 wv = *(const f32x2*)(w1 + k * 64 + jj);
            acc[0] = fmaf(hv, wv[0], acc[0]);
            acc[1] = fmaf(hv, wv[1], acc[1]);
        }
        float v = 0.0f;
#pragma unroll
        for (int ii = 0; ii < 2; ++ii) {
            const int j = jj + ii;
            float a = fmaxf(acc[ii], 0.0f);
            a = (a - mean[j]) * rsqrtf(var[j] + 1e-3f) * gamma[j] + beta[j];
            v = fmaf(a, w2[j], v);
        }
        v += __shfl_down(v, 16);
        v += __shfl_down(v, 8);
        v += __shfl_down(v, 4);
        v += __shfl_down(v, 2);
        v += __shfl_down(v, 1);
        if ((tid & 31) == 0) out[b0 + row] = v + b2[0];
    }
}

extern "C" void kernel_launch(void* const* d_in, const int* in_sizes, int n_in,
                              void* d_out, int out_size, void* d_ws, size_t ws_size,
                              hipStream_t stream) {
    (void)in_sizes; (void)n_in; (void)out_size; (void)d_ws; (void)ws_size;
    const float* inputs  = (const float*)d_in[0];
    const float* Wx      = (const float*)d_in[1];
    const float* Wh      = (const float*)d_in[2];
    const float* bias    = (const float*)d_in[3];
    const float* W_state = (const float*)d_in[4];
    const float* w1      = (const float*)d_in[5];
    const float* b1      = (const float*)d_in[6];
    const float* gamma   = (const float*)d_in[7];
    const float* beta    = (const float*)d_in[8];
    const float* mean    = (const float*)d_in[9];
    const float* var     = (const float*)d_in[10];
    const float* w2      = (const float*)d_in[11];
    const float* b2      = (const float*)d_in[12];
    float* out = (float*)d_out;

    gru_fused<<<32, 512, 0, stream>>>(inputs, Wx, Wh, bias, W_state, w1, b1,
                                      gamma, beta, mean, var, w2, b2, out);
}